// Round 5
// baseline (1851.157 us; speedup 1.0000x reference)
//
#include <hip/hip_runtime.h>
#include <hip/hip_bf16.h>

#define NN 100000
#define NE 1280000
#define DD 64
#define RSHIFT 8             // 256-node dst ranges
#define NRANGE 392           // ceil(NN/256) = 391, padded to 392
#define NPAD (NRANGE * 256)  // 100352 padded node rows

typedef __attribute__((ext_vector_type(8))) short bf16x8;
typedef __attribute__((ext_vector_type(4))) float f32x4;

static __device__ __forceinline__ unsigned short f2bf(float f) {
    __hip_bfloat16 h = __float2bfloat16(f);
    return *reinterpret_cast<unsigned short*>(&h);
}

// ---------------------------------------------------------------------------
// x (fp32) -> bf16 copy. Grid 6250 x 256, 4 elems/thread (exact: 6.4M).
// ---------------------------------------------------------------------------
__global__ __launch_bounds__(256) void f32_to_bf16_kernel(
    const float* __restrict__ in, unsigned short* __restrict__ out)
{
    int i = (blockIdx.x * 256 + threadIdx.x) * 4;
    float4 v = *(const float4*)(in + i);
    ushort4 o;
    o.x = f2bf(v.x); o.y = f2bf(v.y); o.z = f2bf(v.z); o.w = f2bf(v.w);
    *(ushort4*)(out + i) = o;
}

// ---------------------------------------------------------------------------
// B-fragment pre-pack: Bp[layer][t][4 ntiles x 64 lanes][8] bf16. Grid 3.
// k = t*32 + quad*8 + j ; n = nt*16 + m16 ; B[k][n] = k<64 ? Wrel : Wroot.
// ---------------------------------------------------------------------------
__global__ __launch_bounds__(256) void bpack_kernel(
    const float* __restrict__ Wrel1, const float* __restrict__ Wroot1,
    const float* __restrict__ Wrel2, const float* __restrict__ Wroot2,
    const float* __restrict__ Wrel3, const float* __restrict__ Wroot3,
    unsigned short* __restrict__ Bp)
{
    int L = blockIdx.x;
    const float* Wrel  = (L == 0) ? Wrel1  : (L == 1) ? Wrel2  : Wrel3;
    const float* Wroot = (L == 0) ? Wroot1 : (L == 1) ? Wroot2 : Wroot3;
    int tid = threadIdx.x;
    int nt = tid >> 6, lane = tid & 63, quad = lane >> 4, m16 = lane & 15;
    int n = nt * 16 + m16;
    unsigned short* o = Bp + (size_t)L * 4 * 256 * 8;
#pragma unroll
    for (int t = 0; t < 4; ++t)
#pragma unroll
        for (int j = 0; j < 8; ++j) {
            int k = t * 32 + quad * 8 + j;
            float wval = (k < 64) ? Wrel[k * 64 + n] : Wroot[(k - 64) * 64 + n];
            o[((size_t)t * 256 + tid) * 8 + j] = f2bf(wval);
        }
}

// ---------------------------------------------------------------------------
// Range histogram: edges per 256-node dst range (392 bins). LDS-staged.
// ---------------------------------------------------------------------------
__global__ __launch_bounds__(256) void hist392_kernel(
    const int* __restrict__ dst, int* __restrict__ rangeCnt)
{
    __shared__ int h[NRANGE];
    int tid = threadIdx.x;
    if (tid < NRANGE) h[tid] = 0;
    if (tid + 256 < NRANGE) h[tid + 256] = 0;
    __syncthreads();
    int e0 = blockIdx.x * 1024 + tid * 4;
    int4 d4 = *(const int4*)(dst + e0);
    atomicAdd(&h[d4.x >> RSHIFT], 1);
    atomicAdd(&h[d4.y >> RSHIFT], 1);
    atomicAdd(&h[d4.z >> RSHIFT], 1);
    atomicAdd(&h[d4.w >> RSHIFT], 1);
    __syncthreads();
    if (tid < NRANGE && h[tid]) atomicAdd(&rangeCnt[tid], h[tid]);
    if (tid + 256 < NRANGE && h[tid + 256]) atomicAdd(&rangeCnt[tid + 256], h[tid + 256]);
}

// ---------------------------------------------------------------------------
// Exclusive scan of 392 range counts -> rangeBase[393] + gcur (P1 cursors).
// ---------------------------------------------------------------------------
__global__ __launch_bounds__(512) void scan392_kernel(
    const int* __restrict__ rangeCnt, int* __restrict__ rangeBase,
    int* __restrict__ gcur)
{
    __shared__ int sd[512];
    int tid = threadIdx.x;
    int v = (tid < NRANGE) ? rangeCnt[tid] : 0;
    sd[tid] = v;
    __syncthreads();
    for (int o = 1; o < 512; o <<= 1) {
        int t = (tid >= o) ? sd[tid - o] : 0;
        __syncthreads();
        sd[tid] += t;
        __syncthreads();
    }
    if (tid < NRANGE) { int ex = sd[tid] - v; rangeBase[tid] = ex; gcur[tid] = ex; }
    if (tid == 0) rangeBase[NRANGE] = NE;
}

// ---------------------------------------------------------------------------
// P1: bin edges by 256-node dst range into ecoarse (grouped runs, the FINAL
// edge structure -- no p2). 512 thr, 2 edges/thr, wave-shfl scan over 392
// bins (7 waves, last partial). Record: src(17b) | local-dst(8b @ bit17).
// ---------------------------------------------------------------------------
__global__ __launch_bounds__(512) void p1_bin_kernel(
    const int* __restrict__ src, const int* __restrict__ dst,
    const float* __restrict__ w, int* __restrict__ gcur,
    int2* __restrict__ ecoarse)
{
    __shared__ int2 stage[1024];
    __shared__ unsigned short sbkt[1024];
    __shared__ int cnt[NRANGE], ofs[NRANGE], gpos[NRANGE];
    __shared__ int wsum[8];

    int tid = threadIdx.x;
    int e0 = blockIdx.x * 1024 + tid * 2;
    int2   s2 = *(const int2*)(src + e0);
    int2   d2 = *(const int2*)(dst + e0);
    float2 w2 = *(const float2*)(w + e0);

    if (tid < NRANGE) cnt[tid] = 0;
    __syncthreads();

    int ss[2] = {s2.x, s2.y};
    int dd[2] = {d2.x, d2.y};
    float ww[2] = {w2.x, w2.y};
    int b[2], p[2];
#pragma unroll
    for (int i = 0; i < 2; ++i) {
        b[i] = dd[i] >> RSHIFT;
        p[i] = atomicAdd(&cnt[b[i]], 1);
    }
    __syncthreads();

    // wave-level inclusive scan over 392 bins (waves 0..6; wave 6 partial,
    // shfl_up only reads lower active lanes -> safe)
    int sum = 0, v = 0;
    if (tid < NRANGE) {
        v = cnt[tid];
        int lane6 = tid & 63;
        sum = v;
#pragma unroll
        for (int o = 1; o < 64; o <<= 1) {
            int t = __shfl_up(sum, o);
            if (lane6 >= o) sum += t;
        }
        if (lane6 == 63 || tid == NRANGE - 1) wsum[tid >> 6] = sum;
        ofs[tid] = sum - v;               // wave-local exclusive
    }
    __syncthreads();
    if (tid < NRANGE) {
        int wid = tid >> 6;
        int pre = 0;
#pragma unroll
        for (int k = 0; k < 6; ++k) pre += (k < wid) ? wsum[k] : 0;
        ofs[tid] += pre;
        if (v > 0) gpos[tid] = atomicAdd(&gcur[tid], v);
    }
    __syncthreads();

#pragma unroll
    for (int i = 0; i < 2; ++i) {
        int slot = ofs[b[i]] + p[i];
        stage[slot] = make_int2(ss[i] | ((dd[i] & 255) << 17), __float_as_int(ww[i]));
        sbkt[slot] = (unsigned short)b[i];
    }
    __syncthreads();

#pragma unroll
    for (int u = 0; u < 2; ++u) {
        int j = tid + u * 512;
        int bb = sbkt[j];
        ecoarse[gpos[bb] + (j - ofs[bb])] = stage[j];
    }
}

// ---------------------------------------------------------------------------
// FUSED range layer: block = one 256-node range, 512 thr = 8 waves.
// Phase A: LDS fp32 agg[256][64] (64 KB, de-interleaved + XOR-swizzled:
//   channel c of row r lives at word r*64 + ((c>>1) + (c&1)*32) ^ ((r&7)<<2)
//   -> ds_add and MFMA-side ds_read both <=2-way bank aliasing = free).
// Each half-wave handles one edge/slot: broadcast int2 record load, 32 lanes
// load the full 64-ch row as u32 pairs, 2x ds_add_f32. Unroll-8 -> 8 rows
// in flight per wave. No rowptr, no per-node CSR.
// Phase B: 16 m-tiles / 8 waves (2 each): A k0..63 from agg (cvt bf16),
// k64..127 = root row from global; 16 MFMAs per m-tile; bias(+ReLU) store.
// ---------------------------------------------------------------------------
template <bool RELU, bool OUT32>
__global__ __launch_bounds__(512) void fused_range_kernel(
    const unsigned short* __restrict__ hb,   // input node table (NPAD rows)
    const int2* __restrict__ ecoarse,
    const int* __restrict__ rangeBase,
    const unsigned short* __restrict__ Bp,   // [4][256][8] bf16 (this layer)
    const float* __restrict__ brel,
    void* __restrict__ outp)
{
    __shared__ float agg[256 * DD];          // 65536 B exactly

    int tid = threadIdx.x;
    int r = blockIdx.x;
    int n0 = r << RSHIFT;

    // zero agg
    f32x4 z = {0.f, 0.f, 0.f, 0.f};
#pragma unroll
    for (int i = 0; i < 8; ++i)
        *(f32x4*)&agg[(tid + i * 512) * 4] = z;

    int beg = rangeBase[r], end = rangeBase[r + 1];
    __syncthreads();

    int wid = tid >> 6, lane = tid & 63, half = lane >> 5, ch = lane & 31;
    const unsigned int* __restrict__ hw = (const unsigned int*)hb;

    // ---- Phase A: edge-parallel scatter-accumulate ----
    for (int e = beg + wid * 2 + half; e < end; e += 128) {
#pragma unroll
        for (int u = 0; u < 8; ++u) {
            int ei = e + u * 16;
            bool ok = ei < end;
            int2 rec = ecoarse[ok ? ei : beg];
            float wv = ok ? __int_as_float(rec.y) : 0.f;
            int srcN = rec.x & 0x1FFFF;
            int dl = (rec.x >> 17) & 255;
            unsigned v = hw[(size_t)srcN * 32 + ch];
            int o = dl * 64 + ((ch ^ ((dl & 7) << 2)));
            atomicAdd(&agg[o],      wv * __uint_as_float(v << 16));
            atomicAdd(&agg[o + 32], wv * __uint_as_float(v & 0xFFFF0000u));
        }
    }
    __syncthreads();

    // ---- Phase B: dual GEMM out of agg + root rows ----
    int quad = lane >> 4, m16 = lane & 15;
    float bias_nt[4];
#pragma unroll
    for (int nt = 0; nt < 4; ++nt) bias_nt[nt] = brel[nt * 16 + m16];

#pragma unroll
    for (int mi = 0; mi < 2; ++mi) {
        int mt = wid * 2 + mi;
        int rl = mt * 16 + m16;
        int sw = (rl & 7) << 2;
        bf16x8 afr[4];
#pragma unroll
        for (int t = 0; t < 2; ++t) {
            int bo = rl * 64 + ((t * 16 + quad * 4) ^ sw);
            f32x4 ev = *(const f32x4*)&agg[bo];
            f32x4 od = *(const f32x4*)&agg[bo + 32];
#pragma unroll
            for (int i = 0; i < 4; ++i) {
                afr[t][2 * i]     = (short)f2bf(ev[i]);
                afr[t][2 * i + 1] = (short)f2bf(od[i]);
            }
        }
        int node = n0 + mt * 16 + m16;
        const unsigned short* rp = hb + (size_t)node * DD;
        afr[2] = *(const bf16x8*)(rp + quad * 8);
        afr[3] = *(const bf16x8*)(rp + 32 + quad * 8);

#pragma unroll
        for (int nt = 0; nt < 4; ++nt) {
            f32x4 acc = {0.f, 0.f, 0.f, 0.f};
#pragma unroll
            for (int t = 0; t < 4; ++t) {
                bf16x8 bf = *(const bf16x8*)(Bp + (size_t)(t * 256 + nt * 64 + lane) * 8);
                acc = __builtin_amdgcn_mfma_f32_16x16x32_bf16(afr[t], bf, acc, 0, 0, 0);
            }
#pragma unroll
            for (int reg = 0; reg < 4; ++reg) {
                int onode = n0 + mt * 16 + quad * 4 + reg;
                if (onode < NN) {
                    float vv = acc[reg] + bias_nt[nt];
                    if (RELU) vv = fmaxf(vv, 0.f);
                    if (OUT32) ((float*)outp)[(size_t)onode * DD + nt * 16 + m16] = vv;
                    else ((unsigned short*)outp)[(size_t)onode * DD + nt * 16 + m16] = f2bf(vv);
                }
            }
        }
    }
}

extern "C" void kernel_launch(void* const* d_in, const int* in_sizes, int n_in,
                              void* d_out, int out_size, void* d_ws, size_t ws_size,
                              hipStream_t stream)
{
    const float* x     = (const float*)d_in[0];
    const int*   ei    = (const int*)d_in[1];
    const float* w     = (const float*)d_in[2];
    const float* Wrel1 = (const float*)d_in[4];
    const float* brel1 = (const float*)d_in[5];
    const float* Wroot1= (const float*)d_in[6];
    const float* Wrel2 = (const float*)d_in[7];
    const float* brel2 = (const float*)d_in[8];
    const float* Wroot2= (const float*)d_in[9];
    const float* Wrel3 = (const float*)d_in[10];
    const float* brel3 = (const float*)d_in[11];
    const float* Wroot3= (const float*)d_in[12];

    float* out = (float*)d_out;

    // workspace layout (all 16B aligned)
    char* ws = (char*)d_ws;
    int2*  ecoarse = (int2*)ws;                ws += (size_t)NE * 8;            // 10.24 MB (live all layers)
    unsigned short* xb  = (unsigned short*)ws; ws += (size_t)NPAD * DD * 2;     // 12.85 MB
    unsigned short* hb1 = (unsigned short*)ws; ws += (size_t)NPAD * DD * 2;
    unsigned short* hb2 = (unsigned short*)ws; ws += (size_t)NPAD * DD * 2;
    int*   rangeCnt  = (int*)ws;               ws += (size_t)512 * 4;
    int*   rangeBase = (int*)ws;               ws += (size_t)512 * 4;
    int*   gcur      = (int*)ws;               ws += (size_t)512 * 4;
    unsigned short* Bp = (unsigned short*)ws;  // 3 * 16 KB

    const int* src = ei;
    const int* dst = ei + NE;

    // ---- build: range hist -> scan -> single binning pass (no p2, no CSR) ----
    hipMemsetAsync(rangeCnt, 0, NRANGE * 4, stream);
    bpack_kernel<<<3, 256, 0, stream>>>(Wrel1, Wroot1, Wrel2, Wroot2, Wrel3, Wroot3, Bp);
    hist392_kernel<<<1250, 256, 0, stream>>>(dst, rangeCnt);
    scan392_kernel<<<1, 512, 0, stream>>>(rangeCnt, rangeBase, gcur);
    p1_bin_kernel<<<1250, 512, 0, stream>>>(src, dst, w, gcur, ecoarse);

    // ---- xb = bf16(x) ----
    f32_to_bf16_kernel<<<6250, 256, 0, stream>>>(x, xb);

    // ---- 3 fused range layers (ping-pong xb -> hb1 -> hb2 -> out) ----
    fused_range_kernel<true, false><<<NRANGE, 512, 0, stream>>>(
        xb, ecoarse, rangeBase, Bp, brel1, hb1);
    fused_range_kernel<true, false><<<NRANGE, 512, 0, stream>>>(
        hb1, ecoarse, rangeBase, Bp + (size_t)4 * 256 * 8, brel2, hb2);
    fused_range_kernel<false, true><<<NRANGE, 512, 0, stream>>>(
        hb2, ecoarse, rangeBase, Bp + (size_t)8 * 256 * 8, brel3, out);
}

// Round 6
// 308.959 us; speedup vs baseline: 5.9916x; 5.9916x over previous
//
#include <hip/hip_runtime.h>
#include <hip/hip_bf16.h>

#define NN 100000
#define NE 1280000
#define DD 64
#define RSHIFT 9             // 512-node dst ranges
#define NRANGE 196           // ceil(NN/512)
#define NPAD (NRANGE * 512)  // 100352

typedef __attribute__((ext_vector_type(8))) short bf16x8;
typedef __attribute__((ext_vector_type(4))) float f32x4;

static __device__ __forceinline__ unsigned short f2bf(float f) {
    __hip_bfloat16 h = __float2bfloat16(f);
    return *reinterpret_cast<unsigned short*>(&h);
}

// ---------------------------------------------------------------------------
// x (fp32) -> bf16 copy. Grid 6250 x 256, 4 elems/thread (exact: 6.4M).
// ---------------------------------------------------------------------------
__global__ __launch_bounds__(256) void f32_to_bf16_kernel(
    const float* __restrict__ in, unsigned short* __restrict__ out)
{
    int i = (blockIdx.x * 256 + threadIdx.x) * 4;
    float4 v = *(const float4*)(in + i);
    ushort4 o;
    o.x = f2bf(v.x); o.y = f2bf(v.y); o.z = f2bf(v.z); o.w = f2bf(v.w);
    *(ushort4*)(out + i) = o;
}

// ---------------------------------------------------------------------------
// B-fragment pre-pack: Bp[layer][t][256 threads][8] bf16. Grid 3.
// ---------------------------------------------------------------------------
__global__ __launch_bounds__(256) void bpack_kernel(
    const float* __restrict__ Wrel1, const float* __restrict__ Wroot1,
    const float* __restrict__ Wrel2, const float* __restrict__ Wroot2,
    const float* __restrict__ Wrel3, const float* __restrict__ Wroot3,
    unsigned short* __restrict__ Bp)
{
    int L = blockIdx.x;
    const float* Wrel  = (L == 0) ? Wrel1  : (L == 1) ? Wrel2  : Wrel3;
    const float* Wroot = (L == 0) ? Wroot1 : (L == 1) ? Wroot2 : Wroot3;
    int tid = threadIdx.x;
    int wv = tid >> 6, lane = tid & 63, quad = lane >> 4, m16 = lane & 15;
    int n = wv * 16 + m16;
    unsigned short* o = Bp + (size_t)L * 4 * 256 * 8;
#pragma unroll
    for (int t = 0; t < 4; ++t)
#pragma unroll
        for (int j = 0; j < 8; ++j) {
            int k = t * 32 + quad * 8 + j;
            float wval = (k < 64) ? Wrel[k * 64 + n] : Wroot[(k - 64) * 64 + n];
            o[((size_t)t * 256 + tid) * 8 + j] = f2bf(wval);
        }
}

// ---------------------------------------------------------------------------
// Range histogram: count edges per 512-node dst range. LDS-staged.
// ---------------------------------------------------------------------------
__global__ __launch_bounds__(256) void hist2_kernel(
    const int* __restrict__ dst, int* __restrict__ rangeCnt)
{
    __shared__ int h[256];
    int tid = threadIdx.x;
    h[tid] = 0;
    __syncthreads();
    int e0 = blockIdx.x * 1024 + tid * 4;
    int4 d4 = *(const int4*)(dst + e0);
    atomicAdd(&h[d4.x >> RSHIFT], 1);
    atomicAdd(&h[d4.y >> RSHIFT], 1);
    atomicAdd(&h[d4.z >> RSHIFT], 1);
    atomicAdd(&h[d4.w >> RSHIFT], 1);
    __syncthreads();
    if (tid < NRANGE && h[tid]) atomicAdd(&rangeCnt[tid], h[tid]);
}

// ---------------------------------------------------------------------------
// Exclusive scan of 196 range counts -> rangeBase[197] + gcur (P1 cursors).
// ---------------------------------------------------------------------------
__global__ __launch_bounds__(256) void scan196_kernel(
    const int* __restrict__ rangeCnt, int* __restrict__ rangeBase,
    int* __restrict__ gcur, int* __restrict__ rowptr)
{
    __shared__ int sd[256];
    int tid = threadIdx.x;
    int v = (tid < NRANGE) ? rangeCnt[tid] : 0;
    sd[tid] = v;
    __syncthreads();
    for (int o = 1; o < 256; o <<= 1) {
        int t = (tid >= o) ? sd[tid - o] : 0;
        __syncthreads();
        sd[tid] += t;
        __syncthreads();
    }
    if (tid < NRANGE) { int ex = sd[tid] - v; rangeBase[tid] = ex; gcur[tid] = ex; }
    if (tid == 0) { rangeBase[NRANGE] = NE; rowptr[NN] = NE; }
}

// ---------------------------------------------------------------------------
// P1: coarse bin by dst range. 512 thr, 2 edges/thr, wave-shfl scans ->
// only 5 barriers/block. Record: src(17b) | local-dst(9b @ bit17).
// ---------------------------------------------------------------------------
__global__ __launch_bounds__(512) void p1_bin_kernel(
    const int* __restrict__ src, const int* __restrict__ dst,
    const float* __restrict__ w, int* __restrict__ gcur,
    int2* __restrict__ ecoarse)
{
    __shared__ int2 stage[1024];
    __shared__ unsigned char sbkt[1024];
    __shared__ int cnt[256], ofs[256], gpos[256];
    __shared__ int wsum[4];

    int tid = threadIdx.x;
    int e0 = blockIdx.x * 1024 + tid * 2;
    int2   s2 = *(const int2*)(src + e0);
    int2   d2 = *(const int2*)(dst + e0);
    float2 w2 = *(const float2*)(w + e0);

    if (tid < 256) cnt[tid] = 0;
    __syncthreads();

    int ss[2] = {s2.x, s2.y};
    int dd[2] = {d2.x, d2.y};
    float ww[2] = {w2.x, w2.y};
    int b[2], p[2];
#pragma unroll
    for (int i = 0; i < 2; ++i) {
        b[i] = dd[i] >> RSHIFT;
        p[i] = atomicAdd(&cnt[b[i]], 1);
    }
    __syncthreads();

    // wave-level inclusive scan of 256 bins (4 waves x 64 lanes)
    if (tid < 256) {
        int v = cnt[tid];
        int lane6 = tid & 63;
        int sum = v;
#pragma unroll
        for (int o = 1; o < 64; o <<= 1) {
            int t = __shfl_up(sum, o);
            if (lane6 >= o) sum += t;
        }
        if (lane6 == 63) wsum[tid >> 6] = sum;
        ofs[tid] = sum - v;               // wave-local exclusive
    }
    __syncthreads();
    if (tid < 256) {
        int wid = tid >> 6;
        int pre = 0;
#pragma unroll
        for (int k = 0; k < 3; ++k) pre += (k < wid) ? wsum[k] : 0;
        ofs[tid] += pre;
        int cv = cnt[tid];
        if (tid < NRANGE && cv > 0) gpos[tid] = atomicAdd(&gcur[tid], cv);
    }
    __syncthreads();

#pragma unroll
    for (int i = 0; i < 2; ++i) {
        int slot = ofs[b[i]] + p[i];
        stage[slot] = make_int2(ss[i] | ((dd[i] & 511) << 17), __float_as_int(ww[i]));
        sbkt[slot] = (unsigned char)b[i];
    }
    __syncthreads();

#pragma unroll
    for (int u = 0; u < 2; ++u) {
        int j = tid + u * 512;
        int bb = sbkt[j];
        ecoarse[gpos[bb] + (j - ofs[bb])] = stage[j];
    }
}

// ---------------------------------------------------------------------------
// P2: per-range count + wave-shfl scan -> rowptr + cursors, then place.
// Grid NRANGE x 1024 thr. Int LDS atomics (native ds_add_rtn_u32).
// ---------------------------------------------------------------------------
__global__ __launch_bounds__(1024) void p2_place_kernel(
    const int2* __restrict__ ecoarse, const int* __restrict__ rangeBase,
    int* __restrict__ rowptr, int2* __restrict__ ebuf)
{
    __shared__ int cnt[512];
    __shared__ int wsum[8];
    int r = blockIdx.x, tid = threadIdx.x;
    int beg = rangeBase[r], end = rangeBase[r + 1];

    if (tid < 512) cnt[tid] = 0;
    __syncthreads();

    for (int j = beg + tid; j < end; j += 1024) {
        int2 rec = ecoarse[j];
        atomicAdd(&cnt[(rec.x >> 17) & 511], 1);
    }
    __syncthreads();

    // scan 512 counters: 8 waves x 64 lanes, shfl inclusive + cross-wave fix
    int v = 0, sum = 0;
    if (tid < 512) {
        v = cnt[tid]; sum = v;
        int lane6 = tid & 63;
#pragma unroll
        for (int o = 1; o < 64; o <<= 1) {
            int t = __shfl_up(sum, o);
            if (lane6 >= o) sum += t;
        }
        if (lane6 == 63) wsum[tid >> 6] = sum;
    }
    __syncthreads();
    if (tid < 512) {
        int wid = tid >> 6;
        int pre = 0;
#pragma unroll
        for (int k = 0; k < 7; ++k) pre += (k < wid) ? wsum[k] : 0;
        int ex = beg + pre + sum - v;       // exclusive cursor for node tid
        rowptr[(r << RSHIFT) + tid] = ex;
        cnt[tid] = ex;
    }
    __syncthreads();

    for (int j = beg + tid; j < end; j += 1024) {
        int2 rec = ecoarse[j];
        int dl = (rec.x >> 17) & 511;
        int pp = atomicAdd(&cnt[dl], 1);
        ebuf[pp] = make_int2(rec.x & 0x1FFFF, rec.y);
    }
}

// ---------------------------------------------------------------------------
// FUSED layer: CSR gather + dual GEMM + bias (+ReLU). Block = 512 thr =
// 8 waves = 16 nodes. Half-wave per node: 32 lanes = 32 channel pairs,
// unroll-16 slots -> 32 gathers in flight per wave. Edges staged with one
// cooperative ebuf load, distributed by __shfl. Agg + root rows packed into
// LDS in MFMA fragment order, one barrier, waves 0-3 run 4 chained MFMAs +
// epilogue. Ping-pong in/out tables.
// ---------------------------------------------------------------------------
template <bool RELU, bool OUT32>
__global__ __launch_bounds__(512) void fused_layer_kernel(
    const unsigned short* __restrict__ hb,   // input node table (gather + root)
    const int* __restrict__ rowptr,
    const int2* __restrict__ ebuf,
    const unsigned short* __restrict__ Bp,   // [4][256][8] bf16 (this layer)
    const float* __restrict__ brel,
    void* __restrict__ outp)
{
    __shared__ __align__(16) unsigned int AstW[4 * 256];   // 4 KB

    int tid = threadIdx.x;
    int lane = tid & 63;
    int wv = tid >> 6;            // 0..7
    int half = lane >> 5;         // node parity within wave
    int ch = lane & 31;           // channel pair
    int base = blockIdx.x * 16;
    int node = base + wv * 2 + half;

    const unsigned int* __restrict__ hw = (const unsigned int*)hb;

    // B fragments + bias preloaded (only used by waves 0-3) so their L2
    // latency hides under the gather.
    bf16x8 bfrag[4];
    float bias = 0.f;
    if (wv < 4) {
#pragma unroll
        for (int t2 = 0; t2 < 4; ++t2)
            bfrag[t2] = *(const bf16x8*)(Bp + ((size_t)t2 * 256 + tid) * 8);
        bias = brel[(wv << 4) | (lane & 15)];
    }

    // root row (own node) issued early
    unsigned rootp = hw[(size_t)node * 32 + ch];

    int beg = rowptr[node];
    int end = rowptr[node + 1];
    int deg = end - beg;

    float aL[4] = {0.f, 0.f, 0.f, 0.f};
    float aH[4] = {0.f, 0.f, 0.f, 0.f};
    for (int c = 0; c < deg; c += 32) {
        int rem = deg - c;
        int nsl = rem < 32 ? rem : 32;
        int idx = (ch < nsl) ? (c + ch) : c;
        int2 e = ebuf[beg + idx];
        float wt = (ch < nsl) ? __int_as_float(e.y) : 0.f;

        for (int s0 = 0; s0 < nsl; s0 += 16) {
#pragma unroll
            for (int i = 0; i < 16; ++i) {
                int slot = s0 + i;
                bool ok = slot < nsl;
                int sl = (half << 5) | (ok ? slot : 0);
                int sr = __shfl(e.x, sl);
                float w = __shfl(wt, sl);
                w = ok ? w : 0.f;
                unsigned v = hw[(size_t)sr * 32 + ch];
                aL[i & 3] = fmaf(w, __uint_as_float(v << 16), aL[i & 3]);
                aH[i & 3] = fmaf(w, __uint_as_float(v & 0xFFFF0000u), aH[i & 3]);
            }
        }
    }
    float accL = (aL[0] + aL[1]) + (aL[2] + aL[3]);
    float accH = (aH[0] + aH[1]) + (aH[2] + aH[3]);

    // stage agg (k 0..63) and root (k 64..127) pairs in fragment order
    int m = wv * 2 + half;                     // row 0..15
    int t = ch >> 4, q = (ch >> 2) & 3, jj = ch & 3;
    unsigned pack = ((unsigned)f2bf(accH) << 16) | (unsigned)f2bf(accL);
    AstW[t * 256 + (q * 16 + m) * 4 + jj] = pack;
    AstW[(2 + t) * 256 + (q * 16 + m) * 4 + jj] = rootp;
    __syncthreads();

    if (wv < 4) {
        int quad = lane >> 4, m16 = lane & 15;
        int n = wv * 16 + m16;
        f32x4 cacc = {0.f, 0.f, 0.f, 0.f};
#pragma unroll
        for (int t2 = 0; t2 < 4; ++t2) {
            bf16x8 a = *(const bf16x8*)&AstW[t2 * 256 + lane * 4];
            cacc = __builtin_amdgcn_mfma_f32_16x16x32_bf16(a, bfrag[t2], cacc, 0, 0, 0);
        }
#pragma unroll
        for (int reg = 0; reg < 4; ++reg) {
            int row = quad * 4 + reg;
            size_t onode = (size_t)base + row;
            float v2 = cacc[reg] + bias;
            if (RELU) v2 = fmaxf(v2, 0.f);
            if (OUT32) ((float*)outp)[onode * DD + n] = v2;
            else       ((unsigned short*)outp)[onode * DD + n] = f2bf(v2);
        }
    }
}

extern "C" void kernel_launch(void* const* d_in, const int* in_sizes, int n_in,
                              void* d_out, int out_size, void* d_ws, size_t ws_size,
                              hipStream_t stream)
{
    const float* x     = (const float*)d_in[0];
    const int*   ei    = (const int*)d_in[1];
    const float* w     = (const float*)d_in[2];
    const float* Wrel1 = (const float*)d_in[4];
    const float* brel1 = (const float*)d_in[5];
    const float* Wroot1= (const float*)d_in[6];
    const float* Wrel2 = (const float*)d_in[7];
    const float* brel2 = (const float*)d_in[8];
    const float* Wroot2= (const float*)d_in[9];
    const float* Wrel3 = (const float*)d_in[10];
    const float* brel3 = (const float*)d_in[11];
    const float* Wroot3= (const float*)d_in[12];

    float* out = (float*)d_out;

    // workspace: ecoarse->xb alias | ebuf | hb1 | hb2 | ints | Bp
    char* ws = (char*)d_ws;
    int2*  ebuf    = (int2*)ws;                ws += (size_t)NE * 8;            // 10.24 MB
    int2*  ecoarse = (int2*)ws;                                                // aliases xb
    unsigned short* xb  = (unsigned short*)ws; ws += (size_t)NN * DD * 2;       // 12.8 MB (>= ecoarse 10.24)
    unsigned short* hb1 = (unsigned short*)ws; ws += (size_t)NN * DD * 2;       // 12.8 MB
    unsigned short* hb2 = (unsigned short*)ws; ws += (size_t)NN * DD * 2;       // 12.8 MB
    int*   rowptr = (int*)ws;                  ws += (size_t)(NPAD + 16) * 4;
    int*   rangeCnt  = (int*)ws;               ws += (size_t)256 * 4;
    int*   rangeBase = (int*)ws;               ws += (size_t)256 * 4;
    int*   gcur      = (int*)ws;               ws += (size_t)256 * 4;
    unsigned short* Bp = (unsigned short*)ws;  // 3 * 16 KB

    const int* src = ei;
    const int* dst = ei + NE;

    // ---- CSR build: range hist -> scan -> bin -> place ----
    hipMemsetAsync(rangeCnt, 0, NRANGE * 4, stream);
    bpack_kernel<<<3, 256, 0, stream>>>(Wrel1, Wroot1, Wrel2, Wroot2, Wrel3, Wroot3, Bp);
    hist2_kernel<<<1250, 256, 0, stream>>>(dst, rangeCnt);
    scan196_kernel<<<1, 256, 0, stream>>>(rangeCnt, rangeBase, gcur, rowptr);
    p1_bin_kernel<<<1250, 512, 0, stream>>>(src, dst, w, gcur, ecoarse);
    p2_place_kernel<<<NRANGE, 1024, 0, stream>>>(ecoarse, rangeBase, rowptr, ebuf);

    // ---- xb = bf16(x) (ecoarse dead now) ----
    f32_to_bf16_kernel<<<6250, 256, 0, stream>>>(x, xb);

    // ---- 3 fused layers (ping-pong xb -> hb1 -> hb2 -> out) ----
    fused_layer_kernel<true, false><<<NN / 16, 512, 0, stream>>>(
        xb, rowptr, ebuf, Bp, brel1, hb1);
    fused_layer_kernel<true, false><<<NN / 16, 512, 0, stream>>>(
        hb1, rowptr, ebuf, Bp + (size_t)4 * 256 * 8, brel2, hb2);
    fused_layer_kernel<false, true><<<NN / 16, 512, 0, stream>>>(
        hb2, rowptr, ebuf, Bp + (size_t)8 * 256 * 8, brel3, out);
}